// Round 5
// baseline (83.280 us; speedup 1.0000x reference)
//
#include <hip/hip_runtime.h>

#define FIN    1024
#define FOUT2  1024
#define NTASK  20
#define BSZ    256
#define ROWS   32                // output rows per block tile
#define NTILE  (FOUT2 / ROWS)    // 32 tiles per task
#define KCH    128               // K elements per chunk
#define NCHUNK (FIN / KCH)       // 8
#define KC4    (KCH / 4)         // 32 float4 per row-chunk
#define PAD4   1                 // +1 float4 row pad (bank spread)
#define LDW4   (KC4 + PAD4)      // 33 float4 row stride
#define GRP    16                // samples per register group
#define HOFF   (256 * 512)       // h elements before logits in d_out

// Output-stationary: block = (task, 32-row tile). W tile staged global->LDS once
// (1-chunk-ahead register pipeline), waves split K (wave=K-quarter, lane kh-bit
// halves it -> 16-float slice of one row). acc[16] per lane over samples; the
// only reduction is an 8-partial tree via LDS at the end. No shuffles.
__global__ __launch_bounds__(256, 2)
void cond_linear_kernel(const float* __restrict__ x,
                        const int* __restrict__ task_id,
                        const float* __restrict__ W,
                        float* __restrict__ out) {
    __shared__ float wlds[ROWS][4 * LDW4];   // 32 x 132 f32 = 16.9 KB
    __shared__ float xlds[GRP][4 * LDW4];    // 16 x 132 f32 = 8.4 KB
    __shared__ float plds[8][GRP][ROWS];     // 16 KB partials
    __shared__ int   sh_ord[BSZ];
    __shared__ int   wcnt[4];
    __shared__ int   sh_n;

    const int tid  = threadIdx.x;
    const int lane = tid & 63;
    const int wv   = tid >> 6;
    const int t    = blockIdx.x / NTILE;
    const int tile = blockIdx.x % NTILE;
    const int o0   = tile * ROWS;

    // ---- stable per-task sample list (identical to prior passing rounds) ----
    const int my_task = task_id[tid];
    const bool match = (my_task == t);
    const unsigned long long m64 = __ballot(match);
    if (lane == 0) wcnt[wv] = __popcll(m64);
    __syncthreads();
    int base = 0;
    #pragma unroll
    for (int w = 0; w < 4; ++w)
        if (w < wv) base += wcnt[w];
    if (match) {
        const int pos = base + __popcll(m64 & ((1ull << lane) - 1ull));
        sh_ord[pos] = tid;
    }
    if (tid == 0) sh_n = wcnt[0] + wcnt[1] + wcnt[2] + wcnt[3];
    __syncthreads();
    const int n = sh_n;
    if (n == 0) return;

    const float* Wt = W + (size_t)t * ((size_t)FOUT2 * FIN);

    // per-thread staging coordinates (fixed for the whole kernel)
    int wrow[4], wc4[4];
    #pragma unroll
    for (int i = 0; i < 4; ++i) { int f4 = tid + BSZ * i; wrow[i] = f4 >> 5; wc4[i] = f4 & 31; }
    int xm[2], xc4[2];
    #pragma unroll
    for (int i = 0; i < 2; ++i) { int f4 = tid + BSZ * i; xm[i] = f4 >> 5; xc4[i] = f4 & 31; }

    const float4* wsrc[4];
    float4*       wdst[4];
    #pragma unroll
    for (int i = 0; i < 4; ++i) {
        wsrc[i] = (const float4*)(Wt + (size_t)(o0 + wrow[i]) * FIN) + wc4[i];
        wdst[i] = (float4*)&wlds[wrow[i]][0] + wc4[i];
    }

    // this lane's compute slice: row r, K-slice (wv, kh)
    const int r  = lane & 31;
    const int kh = lane >> 5;
    const int j4base = wv * 8 + kh * 4;       // float4 index within row-chunk
    const float4* wrd = (const float4*)&wlds[r][0] + j4base;

    for (int g0 = 0; g0 < n; g0 += GRP) {
        const int gcnt = min(GRP, n - g0);

        // x source/dest for this group
        const float4* xsrc[2];
        float4*       xdst[2];
        bool          xok[2];
        #pragma unroll
        for (int i = 0; i < 2; ++i) {
            xok[i] = (xm[i] < gcnt);
            const int s = sh_ord[g0 + (xok[i] ? xm[i] : 0)];
            xsrc[i] = (const float4*)(x + (size_t)s * FIN) + xc4[i];
            xdst[i] = (float4*)&xlds[xm[i]][0] + xc4[i];
        }

        // prologue: load chunk 0 into registers
        float4 wbuf[4], xbuf[2];
        #pragma unroll
        for (int i = 0; i < 4; ++i) wbuf[i] = wsrc[i][0];
        #pragma unroll
        for (int i = 0; i < 2; ++i) if (xok[i]) xbuf[i] = xsrc[i][0];

        float acc[GRP];
        #pragma unroll
        for (int m = 0; m < GRP; ++m) acc[m] = 0.f;

        for (int kc = 0; kc < NCHUNK; ++kc) {
            __syncthreads();                      // prev compute done reading LDS
            #pragma unroll
            for (int i = 0; i < 4; ++i) wdst[i][0] = wbuf[i];
            #pragma unroll
            for (int i = 0; i < 2; ++i) if (xok[i]) xdst[i][0] = xbuf[i];

            if (kc + 1 < NCHUNK) {                // issue next chunk (hidden under compute)
                const int kof = (kc + 1) * KC4;
                #pragma unroll
                for (int i = 0; i < 4; ++i) wbuf[i] = wsrc[i][kof];
                #pragma unroll
                for (int i = 0; i < 2; ++i) if (xok[i]) xbuf[i] = xsrc[i][kof];
            }
            __syncthreads();                      // staged chunk visible

            #pragma unroll
            for (int jj = 0; jj < 4; ++jj) {
                const float4 w4 = wrd[jj];
                #pragma unroll
                for (int mb = 0; mb < 4; ++mb) {
                    if (mb * 4 < gcnt) {
                        #pragma unroll
                        for (int mm = 0; mm < 4; ++mm) {
                            const int m = mb * 4 + mm;
                            const float4 x4 = ((const float4*)&xlds[m][0])[j4base + jj];
                            acc[m] += w4.x * x4.x;
                            acc[m] += w4.y * x4.y;
                            acc[m] += w4.z * x4.z;
                            acc[m] += w4.w * x4.w;
                        }
                    }
                }
            }
        }

        // ---- write 8 partials per output, tree-combine, emit logits + h ----
        const int q = wv * 2 + kh;
        #pragma unroll
        for (int mb = 0; mb < 4; ++mb) {
            if (mb * 4 < gcnt) {
                #pragma unroll
                for (int mm = 0; mm < 4; ++mm) {
                    const int m = mb * 4 + mm;
                    plds[q][m][r] = acc[m];
                }
            }
        }
        __syncthreads();

        for (int idx = tid; idx < gcnt * 16; idx += BSZ) {
            const int m  = idx >> 4;
            const int rp = idx & 15;
            const int r0 = rp * 2, r1 = r0 + 1;
            const int s  = sh_ord[g0 + m];
            const float v0 = ((plds[0][m][r0] + plds[1][m][r0]) + (plds[2][m][r0] + plds[3][m][r0]))
                           + ((plds[4][m][r0] + plds[5][m][r0]) + (plds[6][m][r0] + plds[7][m][r0]));
            const float v1 = ((plds[0][m][r1] + plds[1][m][r1]) + (plds[2][m][r1] + plds[3][m][r1]))
                           + ((plds[4][m][r1] + plds[5][m][r1]) + (plds[6][m][r1] + plds[7][m][r1]));
            out[HOFF + (size_t)s * FOUT2 + o0 + r0] = v0;
            out[HOFF + (size_t)s * FOUT2 + o0 + r1] = v1;
            out[(size_t)s * (FOUT2 / 2) + ((o0 + r0) >> 1)] = (v0 >= v1) ? 1.0f : 0.0f;
        }
        __syncthreads();                          // LDS reused by next group
    }
}

extern "C" void kernel_launch(void* const* d_in, const int* in_sizes, int n_in,
                              void* d_out, int out_size, void* d_ws, size_t ws_size,
                              hipStream_t stream) {
    const float* x       = (const float*)d_in[0];
    const int*   task_id = (const int*)d_in[1];
    const float* W       = (const float*)d_in[2];
    float*       out     = (float*)d_out;

    dim3 grid(NTASK * NTILE);
    dim3 block(BSZ);
    hipLaunchKernelGGL(cond_linear_kernel, grid, block, 0, stream,
                       x, task_id, W, out);
}

// Round 6
// 35.571 us; speedup vs baseline: 2.3412x; 2.3412x over previous
//
#include <hip/hip_runtime.h>

#define FIN   1024
#define FOUT2 1024
#define NTASK 20
#define BSZ   256
#define HOFF  (256 * 512)        // h output elements before logits

// Round-4 skeleton (best: 39us) with two fixes:
//  1) W rows pinned in VGPRs via asm keep-alive -> W read ONCE per block
//     (kills the ~1 GB L2 re-read traffic that bound round 4).
//  2) Sample-pair processing: 8 interleaved butterfly chains (vs 4) + 2-deep
//     x prefetch. Per-dot FMA order and butterfly order bit-identical.
__global__ __launch_bounds__(256, 2)
void cond_linear_kernel(const float* __restrict__ x,
                        const int* __restrict__ task_id,
                        const float* __restrict__ W,
                        float* __restrict__ out) {
    __shared__ int sh_ord[BSZ];
    __shared__ int wcnt[4];
    __shared__ int sh_n;

    const int tid  = threadIdx.x;
    const int lane = tid & 63;
    const int wv   = tid >> 6;
    const int t    = blockIdx.x >> 6;     // task id
    const int tile = blockIdx.x & 63;     // 64 tiles of 16 outputs
    const int o0   = tile * 16 + wv * 4;  // this wave's 4 output rows

    // ---- stable per-task sample list (identical to prior passing rounds) ----
    const int my_task = task_id[tid];
    const bool match = (my_task == t);
    const unsigned long long m64 = __ballot(match);
    if (lane == 0) wcnt[wv] = __popcll(m64);
    __syncthreads();
    int base = 0;
    #pragma unroll
    for (int w = 0; w < 4; ++w)
        if (w < wv) base += wcnt[w];
    if (match) {
        const int pos = base + __popcll(m64 & ((1ull << lane) - 1ull));
        sh_ord[pos] = tid;
    }
    if (tid == 0) sh_n = wcnt[0] + wcnt[1] + wcnt[2] + wcnt[3];
    __syncthreads();
    const int n = sh_n;
    if (n == 0) return;

    // ---- this wave's 4 W rows: load once, PIN in VGPRs (no remat possible) ----
    const float* Wt = W + (size_t)t * (FOUT2 * FIN);
    float4 wr[4][4];
    #pragma unroll
    for (int r = 0; r < 4; ++r) {
        const float4* wp = (const float4*)(Wt + (size_t)(o0 + r) * FIN);
        #pragma unroll
        for (int p = 0; p < 4; ++p)
            wr[r][p] = wp[p * 64 + lane];
    }
    #pragma unroll
    for (int r = 0; r < 4; ++r)
        #pragma unroll
        for (int p = 0; p < 4; ++p)
            asm volatile("" : "+v"(wr[r][p].x), "+v"(wr[r][p].y),
                              "+v"(wr[r][p].z), "+v"(wr[r][p].w));

    // ---- preload first sample pair ----
    int sa = sh_ord[0];
    int sb = sh_ord[(n > 1) ? 1 : 0];
    float4 xa[4], xb[4];
    #pragma unroll
    for (int p = 0; p < 4; ++p)
        xa[p] = ((const float4*)(x + (size_t)sa * FIN))[p * 64 + lane];
    #pragma unroll
    for (int p = 0; p < 4; ++p)
        xb[p] = ((const float4*)(x + (size_t)sb * FIN))[p * 64 + lane];

    for (int i = 0; i + 1 < n; i += 2) {
        // prefetch next pair (falls back to already-loaded indices at the tail)
        const int ia2 = (i + 2 < n) ? i + 2 : i;
        const int ib2 = (i + 3 < n) ? i + 3 : ia2;
        const int na_s = sh_ord[ia2];
        const int nb_s = sh_ord[ib2];
        float4 na[4], nb[4];
        #pragma unroll
        for (int p = 0; p < 4; ++p)
            na[p] = ((const float4*)(x + (size_t)na_s * FIN))[p * 64 + lane];
        #pragma unroll
        for (int p = 0; p < 4; ++p)
            nb[p] = ((const float4*)(x + (size_t)nb_s * FIN))[p * 64 + lane];

        float a0 = 0.f, a1 = 0.f, a2 = 0.f, a3 = 0.f;
        float b0 = 0.f, b1 = 0.f, b2 = 0.f, b3 = 0.f;
        #pragma unroll
        for (int p = 0; p < 4; ++p) {
            const float4 u = xa[p];
            const float4 v = xb[p];
            a0 += wr[0][p].x * u.x + wr[0][p].y * u.y + wr[0][p].z * u.z + wr[0][p].w * u.w;
            a1 += wr[1][p].x * u.x + wr[1][p].y * u.y + wr[1][p].z * u.z + wr[1][p].w * u.w;
            a2 += wr[2][p].x * u.x + wr[2][p].y * u.y + wr[2][p].z * u.z + wr[2][p].w * u.w;
            a3 += wr[3][p].x * u.x + wr[3][p].y * u.y + wr[3][p].z * u.z + wr[3][p].w * u.w;
            b0 += wr[0][p].x * v.x + wr[0][p].y * v.y + wr[0][p].z * v.z + wr[0][p].w * v.w;
            b1 += wr[1][p].x * v.x + wr[1][p].y * v.y + wr[1][p].z * v.z + wr[1][p].w * v.w;
            b2 += wr[2][p].x * v.x + wr[2][p].y * v.y + wr[2][p].z * v.z + wr[2][p].w * v.w;
            b3 += wr[3][p].x * v.x + wr[3][p].y * v.y + wr[3][p].z * v.z + wr[3][p].w * v.w;
        }

        #pragma unroll
        for (int sh = 32; sh >= 1; sh >>= 1) {
            a0 += __shfl_xor(a0, sh, 64);
            a1 += __shfl_xor(a1, sh, 64);
            a2 += __shfl_xor(a2, sh, 64);
            a3 += __shfl_xor(a3, sh, 64);
            b0 += __shfl_xor(b0, sh, 64);
            b1 += __shfl_xor(b1, sh, 64);
            b2 += __shfl_xor(b2, sh, 64);
            b3 += __shfl_xor(b3, sh, 64);
        }
        if (lane == 0) {
            float* la = out + HOFF + (size_t)sa * FOUT2 + o0;
            la[0] = a0; la[1] = a1; la[2] = a2; la[3] = a3;
            out[(size_t)sa * (FOUT2 / 2) + (o0 >> 1)]     = (a0 >= a1) ? 1.0f : 0.0f;
            out[(size_t)sa * (FOUT2 / 2) + (o0 >> 1) + 1] = (a2 >= a3) ? 1.0f : 0.0f;
            float* lb = out + HOFF + (size_t)sb * FOUT2 + o0;
            lb[0] = b0; lb[1] = b1; lb[2] = b2; lb[3] = b3;
            out[(size_t)sb * (FOUT2 / 2) + (o0 >> 1)]     = (b0 >= b1) ? 1.0f : 0.0f;
            out[(size_t)sb * (FOUT2 / 2) + (o0 >> 1) + 1] = (b2 >= b3) ? 1.0f : 0.0f;
        }

        sa = na_s; sb = nb_s;
        #pragma unroll
        for (int p = 0; p < 4; ++p) { xa[p] = na[p]; xb[p] = nb[p]; }
    }

    if (n & 1) {  // tail sample: xa holds sh_ord[n-1] by construction
        float a0 = 0.f, a1 = 0.f, a2 = 0.f, a3 = 0.f;
        #pragma unroll
        for (int p = 0; p < 4; ++p) {
            const float4 u = xa[p];
            a0 += wr[0][p].x * u.x + wr[0][p].y * u.y + wr[0][p].z * u.z + wr[0][p].w * u.w;
            a1 += wr[1][p].x * u.x + wr[1][p].y * u.y + wr[1][p].z * u.z + wr[1][p].w * u.w;
            a2 += wr[2][p].x * u.x + wr[2][p].y * u.y + wr[2][p].z * u.z + wr[2][p].w * u.w;
            a3 += wr[3][p].x * u.x + wr[3][p].y * u.y + wr[3][p].z * u.z + wr[3][p].w * u.w;
        }
        #pragma unroll
        for (int sh = 32; sh >= 1; sh >>= 1) {
            a0 += __shfl_xor(a0, sh, 64);
            a1 += __shfl_xor(a1, sh, 64);
            a2 += __shfl_xor(a2, sh, 64);
            a3 += __shfl_xor(a3, sh, 64);
        }
        if (lane == 0) {
            float* la = out + HOFF + (size_t)sa * FOUT2 + o0;
            la[0] = a0; la[1] = a1; la[2] = a2; la[3] = a3;
            out[(size_t)sa * (FOUT2 / 2) + (o0 >> 1)]     = (a0 >= a1) ? 1.0f : 0.0f;
            out[(size_t)sa * (FOUT2 / 2) + (o0 >> 1) + 1] = (a2 >= a3) ? 1.0f : 0.0f;
        }
    }
}

extern "C" void kernel_launch(void* const* d_in, const int* in_sizes, int n_in,
                              void* d_out, int out_size, void* d_ws, size_t ws_size,
                              hipStream_t stream) {
    const float* x       = (const float*)d_in[0];
    const int*   task_id = (const int*)d_in[1];
    const float* W       = (const float*)d_in[2];
    float*       out     = (float*)d_out;

    dim3 grid(NTASK * 64);
    dim3 block(BSZ);
    hipLaunchKernelGGL(cond_linear_kernel, grid, block, 0, stream,
                       x, task_id, W, out);
}

// Round 7
// 31.605 us; speedup vs baseline: 2.6351x; 1.1255x over previous
//
#include <hip/hip_runtime.h>

#define FIN   1024
#define FOUT2 1024
#define NTASK 20
#define BSZ   256
#define HOFF  (256 * 512)        // h output elements before logits

// Round-6 skeleton (pinned W, 35.6us) + two levers:
//  1) sample slot-split: grid 20*64*2; slot0 = samples [0,ceil(n/2)), slot1 = rest.
//     Slots of a tile sit 64 apart in blockIdx (0 mod 8) -> same XCD L2 for W.
//  2) folded reduction tree: 17 swizzles instead of 48; bit-identical to the
//     full butterfly (every lane of a butterfly holds the same bitwise value).
__global__ __launch_bounds__(256, 2)
void cond_linear_kernel(const float* __restrict__ x,
                        const int* __restrict__ task_id,
                        const float* __restrict__ W,
                        float* __restrict__ out) {
    __shared__ int sh_ord[BSZ];
    __shared__ int wcnt[4];
    __shared__ int sh_n;

    const int tid  = threadIdx.x;
    const int lane = tid & 63;
    const int wv   = tid >> 6;
    const int bx   = blockIdx.x;
    const int t    = bx >> 7;             // task id (128 blocks per task)
    const int rem  = bx & 127;
    const int tile = rem & 63;            // 64 tiles of 16 outputs
    const int slot = rem >> 6;            // 2 sample slots
    const int o0   = tile * 16 + wv * 4;  // this wave's 4 output rows

    // ---- stable per-task sample list (identical to prior passing rounds) ----
    const int my_task = task_id[tid];
    const bool match = (my_task == t);
    const unsigned long long m64 = __ballot(match);
    if (lane == 0) wcnt[wv] = __popcll(m64);
    __syncthreads();
    int base = 0;
    #pragma unroll
    for (int w = 0; w < 4; ++w)
        if (w < wv) base += wcnt[w];
    if (match) {
        const int pos = base + __popcll(m64 & ((1ull << lane) - 1ull));
        sh_ord[pos] = tid;
    }
    if (tid == 0) sh_n = wcnt[0] + wcnt[1] + wcnt[2] + wcnt[3];
    __syncthreads();
    const int n = sh_n;
    const int half = (n + 1) >> 1;
    const int i0 = slot ? half : 0;
    const int i1 = slot ? n    : half;
    if (i0 >= i1) return;

    // ---- this wave's 4 W rows: load once, PIN in VGPRs (no remat possible) ----
    const float* Wt = W + (size_t)t * (FOUT2 * FIN);
    float4 wr[4][4];
    #pragma unroll
    for (int r = 0; r < 4; ++r) {
        const float4* wp = (const float4*)(Wt + (size_t)(o0 + r) * FIN);
        #pragma unroll
        for (int p = 0; p < 4; ++p)
            wr[r][p] = wp[p * 64 + lane];
    }
    #pragma unroll
    for (int r = 0; r < 4; ++r)
        #pragma unroll
        for (int p = 0; p < 4; ++p)
            asm volatile("" : "+v"(wr[r][p].x), "+v"(wr[r][p].y),
                              "+v"(wr[r][p].z), "+v"(wr[r][p].w));

    // lane identity bits for the folded tree
    const bool hi32 = (lane & 32) != 0;
    const bool hi16 = (lane & 16) != 0;
    const bool hi8  = (lane & 8)  != 0;

    // ---- preload first sample pair ----
    int sa = sh_ord[i0];
    int sb = sh_ord[(i0 + 1 < i1) ? i0 + 1 : i1 - 1];
    float4 xa[4], xb[4];
    #pragma unroll
    for (int p = 0; p < 4; ++p)
        xa[p] = ((const float4*)(x + (size_t)sa * FIN))[p * 64 + lane];
    #pragma unroll
    for (int p = 0; p < 4; ++p)
        xb[p] = ((const float4*)(x + (size_t)sb * FIN))[p * 64 + lane];

    for (int i = i0; i < i1; i += 2) {
        // prefetch next pair (clamped; tail duplicates are benign)
        const int ina = (i + 2 < i1) ? i + 2 : i1 - 1;
        const int inb = (i + 3 < i1) ? i + 3 : i1 - 1;
        const int na_s = sh_ord[ina];
        const int nb_s = sh_ord[inb];
        float4 na[4], nb[4];
        #pragma unroll
        for (int p = 0; p < 4; ++p)
            na[p] = ((const float4*)(x + (size_t)na_s * FIN))[p * 64 + lane];
        #pragma unroll
        for (int p = 0; p < 4; ++p)
            nb[p] = ((const float4*)(x + (size_t)nb_s * FIN))[p * 64 + lane];

        float a0 = 0.f, a1 = 0.f, a2 = 0.f, a3 = 0.f;
        float b0 = 0.f, b1 = 0.f, b2 = 0.f, b3 = 0.f;
        #pragma unroll
        for (int p = 0; p < 4; ++p) {
            const float4 u = xa[p];
            const float4 v = xb[p];
            a0 += wr[0][p].x * u.x + wr[0][p].y * u.y + wr[0][p].z * u.z + wr[0][p].w * u.w;
            a1 += wr[1][p].x * u.x + wr[1][p].y * u.y + wr[1][p].z * u.z + wr[1][p].w * u.w;
            a2 += wr[2][p].x * u.x + wr[2][p].y * u.y + wr[2][p].z * u.z + wr[2][p].w * u.w;
            a3 += wr[3][p].x * u.x + wr[3][p].y * u.y + wr[3][p].z * u.z + wr[3][p].w * u.w;
            b0 += wr[0][p].x * v.x + wr[0][p].y * v.y + wr[0][p].z * v.z + wr[0][p].w * v.w;
            b1 += wr[1][p].x * v.x + wr[1][p].y * v.y + wr[1][p].z * v.z + wr[1][p].w * v.w;
            b2 += wr[2][p].x * v.x + wr[2][p].y * v.y + wr[2][p].z * v.z + wr[2][p].w * v.w;
            b3 += wr[3][p].x * v.x + wr[3][p].y * v.y + wr[3][p].z * v.z + wr[3][p].w * v.w;
        }

        // ---- folded reduction tree (bit-identical to full 32..1 butterfly) ----
        // stage 32 on all 8 values
        const float t0 = a0 + __shfl_xor(a0, 32, 64);
        const float t1 = a1 + __shfl_xor(a1, 32, 64);
        const float t2 = a2 + __shfl_xor(a2, 32, 64);
        const float t3 = a3 + __shfl_xor(a3, 32, 64);
        const float t4 = b0 + __shfl_xor(b0, 32, 64);
        const float t5 = b1 + __shfl_xor(b1, 32, 64);
        const float t6 = b2 + __shfl_xor(b2, 32, 64);
        const float t7 = b3 + __shfl_xor(b3, 32, 64);
        // fold by bit32: lanes>=32 carry sample b
        float w0 = hi32 ? t4 : t0;
        float w1 = hi32 ? t5 : t1;
        float w2 = hi32 ? t6 : t2;
        float w3 = hi32 ? t7 : t3;
        // stage 16 + fold by bit16 (row high bit)
        w0 += __shfl_xor(w0, 16, 64);
        w1 += __shfl_xor(w1, 16, 64);
        w2 += __shfl_xor(w2, 16, 64);
        w3 += __shfl_xor(w3, 16, 64);
        float u0 = hi16 ? w2 : w0;
        float u1 = hi16 ? w3 : w1;
        // stage 8 + fold by bit8 (row low bit)
        u0 += __shfl_xor(u0, 8, 64);
        u1 += __shfl_xor(u1, 8, 64);
        float z = hi8 ? u1 : u0;
        // stages 4,2,1
        z += __shfl_xor(z, 4, 64);
        z += __shfl_xor(z, 2, 64);
        z += __shfl_xor(z, 1, 64);
        // partner row (r^1) for the h compare
        const float zp = __shfl_xor(z, 8, 64);

        // lane identity: r = bit8 + 2*bit16, s = bit32
        const int r_id = (hi8 ? 1 : 0) + (hi16 ? 2 : 0);
        const int s_idx = hi32 ? sb : sa;
        if ((lane & 7) == 0) {
            out[HOFF + (size_t)s_idx * FOUT2 + o0 + r_id] = z;
            if (!hi8) {   // even row: h = (logit_even >= logit_odd)
                out[(size_t)s_idx * (FOUT2 / 2) + (o0 >> 1) + (hi16 ? 1 : 0)]
                    = (z >= zp) ? 1.0f : 0.0f;
            }
        }

        sa = na_s; sb = nb_s;
        #pragma unroll
        for (int p = 0; p < 4; ++p) { xa[p] = na[p]; xb[p] = nb[p]; }
    }
}

extern "C" void kernel_launch(void* const* d_in, const int* in_sizes, int n_in,
                              void* d_out, int out_size, void* d_ws, size_t ws_size,
                              hipStream_t stream) {
    const float* x       = (const float*)d_in[0];
    const int*   task_id = (const int*)d_in[1];
    const float* W       = (const float*)d_in[2];
    float*       out     = (float*)d_out;

    dim3 grid(NTASK * 64 * 2);
    dim3 block(BSZ);
    hipLaunchKernelGGL(cond_linear_kernel, grid, block, 0, stream,
                       x, task_id, W, out);
}